// Round 1
// 721.062 us; speedup vs baseline: 1.1040x; 1.1040x over previous
//
#include <hip/hip_runtime.h>
#include <math.h>

typedef unsigned short u16;
typedef __attribute__((ext_vector_type(4))) float f32x4;
typedef __attribute__((ext_vector_type(8))) __bf16 bf16x8;
typedef __attribute__((ext_vector_type(4))) unsigned short u16x4;
typedef __attribute__((ext_vector_type(8))) unsigned short u16x8;

// async global->LDS, 16B per lane; LDS dest must be wave-uniform base + lane*16
#define GLL16(gp, lp) __builtin_amdgcn_global_load_lds( \
    (__attribute__((address_space(1))) void*)(void*)(gp), \
    (__attribute__((address_space(3))) void*)(void*)(lp), 16, 0, 0)

__device__ __forceinline__ u16 f2bf(float x) {            // RNE
    unsigned u = __float_as_uint(x);
    return (u16)((u + 0x7FFFu + ((u >> 16) & 1u)) >> 16);
}
__device__ __forceinline__ float bf2f(u16 h) { return __uint_as_float(((unsigned)h) << 16); }

__device__ __forceinline__ f32x4 mfma16(bf16x8 a, bf16x8 b, f32x4 c) {
    return __builtin_amdgcn_mfma_f32_16x16x32_bf16(a, b, c, 0, 0, 0);
}

// ---------------- fp32 -> bf16 conversion ----------------
__global__ void cvt_f32_bf16(const float* __restrict__ s, u16* __restrict__ d, int n4) {
    int i = blockIdx.x * 256 + threadIdx.x;
    if (i < n4) {
        float4 v = ((const float4*)s)[i];
        u16x4 o = { f2bf(v.x), f2bf(v.y), f2bf(v.z), f2bf(v.w) };
        ((u16x4*)d)[i] = o;
    }
}

// ---------------- rope table: cos/sin of 2*theta (double rotary = rotate by 2theta) ----
__global__ void rope_table_k(float2* __restrict__ tab) {
    int id = blockIdx.x * 256 + threadIdx.x;   // 2048*64
    int t = id >> 6, j = id & 63;
    float freq = exp2f(-((float)(2 * j) / 128.f) * 13.287712379549449f);
    float ang = 2.f * (float)t * freq;
    float sv, cv;
    sincosf(ang, &sv, &cv);
    float2 r; r.x = cv; r.y = sv;
    tab[id] = r;
}

// ---------------- NT GEMM: C[m][n] = sum_k A[m][k] * B[n][k], 128x128 tile, BK=64 ----
// K-loop: double-buffered LDS (2 x (As 16KB + Bs 16KB)), raw s_barrier + counted
// vmcnt(8) so next-tile global_load_lds stays in flight across compute (T3/T4).
// LDS rows are 128B (8 x 16B chunks); chunk index XOR'd with (row&7) to kill the
// 8-way ds_read_b128 bank conflict; global SOURCE is pre-swizzled (linear LDS dest,
// global_load_lds constraint), ds_read applies the same XOR.
// MODE 0: fused QKV; rope+scale fused into Q/K epilogue; V written transposed.
// MODE 1: fp32 Out (M x 2048)
template <int MODE>
__global__ __launch_bounds__(256) void gemm_nt(const u16* __restrict__ A, const u16* __restrict__ Bw,
                                               u16* __restrict__ Qo, u16* __restrict__ Ko,
                                               u16* __restrict__ Vt, float* __restrict__ Out,
                                               const float2* __restrict__ tab, float qscale, int K) {
    __shared__ u16 smem[32768];   // buf b: As at b*16384, Bs at b*16384+8192 (u16 idx)
    const int tid = threadIdx.x;
    const int lane = tid & 63;
    const int qd = lane >> 4, ln = lane & 15;
    const int wid = tid >> 6;
    const int wx = wid & 1, wy = wid >> 1;

    constexpr int NBY = (MODE == 0) ? 48 : 16;
    const int id = blockIdx.y * 64 + blockIdx.x;
    const int xcd = id & 7, slot = id >> 3;
    const int m0 = ((slot / NBY) * 8 + xcd) * 128;
    const int n0 = (slot % NBY) * 128;

    // staging map: tile = 128 rows x 64 k (= 1024 16B chunks), 4 chunks/thread/matrix.
    // LDS dest linear; source k-chunk pre-swizzled: kc_src = kc ^ (row&7).
    int asrc[4], bsrc[4], ldst[4];
#pragma unroll
    for (int l = 0; l < 4; ++l) {
        const int i = l * 256 + tid;
        const int r = i >> 3;
        const int kc = (i & 7) ^ (r & 7);
        asrc[l] = (m0 + r) * K + kc * 8;
        bsrc[l] = (n0 + r) * K + kc * 8;
        ldst[l] = i * 8;
    }
    const u16* Ag = A;
    const u16* Bg = Bw;

    f32x4 acc[4][4];
#pragma unroll
    for (int mi = 0; mi < 4; ++mi)
#pragma unroll
        for (int ni = 0; ni < 4; ++ni) acc[mi][ni] = f32x4{0.f, 0.f, 0.f, 0.f};

    const int arow = (wy * 64 + ln) * 64;      // u16 idx of this lane's A row base
    const int brow = (wx * 64 + ln) * 64;
    const int cx[2] = { (qd ^ (ln & 7)) * 8, ((qd + 4) ^ (ln & 7)) * 8 };  // swizzled k-chunk offs

    auto compute = [&](int buf) {
        const u16* As = &smem[buf * 16384];
        const u16* Bs = As + 8192;
#pragma unroll
        for (int ks = 0; ks < 2; ++ks) {
            bf16x8 af[4], bfr[4];
#pragma unroll
            for (int i = 0; i < 4; ++i) af[i] = *(const bf16x8*)&As[arow + i * 1024 + cx[ks]];
#pragma unroll
            for (int i = 0; i < 4; ++i) bfr[i] = *(const bf16x8*)&Bs[brow + i * 1024 + cx[ks]];
#pragma unroll
            for (int mi = 0; mi < 4; ++mi)
#pragma unroll
                for (int ni = 0; ni < 4; ++ni)
                    acc[mi][ni] = mfma16(af[mi], bfr[ni], acc[mi][ni]);
        }
    };

    const int niter = K >> 6;                  // 32
    // prologue: tile 0 -> buf0
#pragma unroll
    for (int l = 0; l < 4; ++l) GLL16(Ag + asrc[l], &smem[ldst[l]]);
#pragma unroll
    for (int l = 0; l < 4; ++l) GLL16(Bg + bsrc[l], &smem[8192 + ldst[l]]);
    Ag += 64; Bg += 64;

    for (int kt = 0; kt < niter - 1; ++kt) {
        // barrier(1): all waves' prior-iter ds_reads retired (they retire before the
        // MFMAs that consume them) -> safe to overwrite buf^1 via global_load_lds.
        asm volatile("s_barrier" ::: "memory");
        u16* dA = &smem[((kt + 1) & 1) * 16384];
#pragma unroll
        for (int l = 0; l < 4; ++l) GLL16(Ag + asrc[l], &dA[ldst[l]]);
#pragma unroll
        for (int l = 0; l < 4; ++l) GLL16(Bg + bsrc[l], &dA[8192 + ldst[l]]);
        Ag += 64; Bg += 64;
        // counted wait: 8 newer (tile kt+1) loads stay in flight; tile kt landed.
        asm volatile("s_waitcnt vmcnt(8)" ::: "memory");
        asm volatile("s_barrier" ::: "memory");
        compute(kt & 1);
    }
    asm volatile("s_barrier" ::: "memory");
    asm volatile("s_waitcnt vmcnt(0)" ::: "memory");
    asm volatile("s_barrier" ::: "memory");
    compute((niter - 1) & 1);

    __syncthreads();   // K-loop LDS dead; epilogue reuses it

    if constexpr (MODE == 0) {
        const int sec = n0 >> 11;   // 0=Q 1=K 2=V, uniform per block
        if (sec <= 1) {
            // stage C tile [m 128][d 128], chunk-swizzled: chunk' = (d>>3) ^ (m&15)
#pragma unroll
            for (int mi = 0; mi < 4; ++mi)
#pragma unroll
                for (int ni = 0; ni < 4; ++ni) {
                    const int col = wx * 64 + ni * 16 + ln;
                    const int cc = col >> 3, co = col & 7;
#pragma unroll
                    for (int r = 0; r < 4; ++r) {
                        const int row = wy * 64 + mi * 16 + qd * 4 + r;
                        smem[row * 128 + ((cc ^ (row & 15)) * 8) + co] = f2bf(acc[mi][ni][r]);
                    }
                }
            __syncthreads();
            const float qs = (sec == 0) ? qscale : 1.0f;
            u16* dstb = (sec == 0 ? Qo : Ko);
#pragma unroll
            for (int it = 0; it < 4; ++it) {
                const int c = it * 256 + tid;          // 1024 items: m=c>>3 (0..127), d-octet=c&7
                const int m = c >> 3, d8 = c & 7;
                const u16x8 lo = *(const u16x8*)&smem[m * 128 + ((d8 ^ (m & 15)) * 8)];
                const u16x8 hi = *(const u16x8*)&smem[m * 128 + (((d8 + 8) ^ (m & 15)) * 8)];
                const int t = (m0 + m) & 2047;
                const float2* tb = tab + t * 64 + d8 * 8;
                u16x8 o1, o2;
#pragma unroll
                for (int i = 0; i < 8; ++i) {
                    const float x1 = bf2f(lo[i]), x2 = bf2f(hi[i]);
                    const float2 cs = tb[i];
                    o1[i] = f2bf((x1 * cs.x + x2 * cs.y) * qs);
                    o2[i] = f2bf((x2 * cs.x - x1 * cs.y) * qs);
                }
                u16* dst = dstb + (size_t)(m0 + m) * 2048 + (n0 & 2047) + d8 * 8;
                *(u16x8*)dst = o1;
                *(u16x8*)(dst + 64) = o2;
            }
        } else {
            // V transpose: stage [n 128][m 128] chunk-swizzled, stream out rows of Vt
            const int bb = m0 >> 11;
#pragma unroll
            for (int mi = 0; mi < 4; ++mi) {
                const int mbase = wy * 64 + mi * 16 + qd * 4;
                const int mch = mbase >> 3, moff = mbase & 7;
#pragma unroll
                for (int ni = 0; ni < 4; ++ni) {
                    const int nl = wx * 64 + ni * 16 + ln;
                    u16x4 pk = { f2bf(acc[mi][ni][0]), f2bf(acc[mi][ni][1]),
                                 f2bf(acc[mi][ni][2]), f2bf(acc[mi][ni][3]) };
                    *(u16x4*)&smem[nl * 128 + ((mch ^ (nl & 15)) * 8) + moff] = pk;
                }
            }
            __syncthreads();
#pragma unroll
            for (int i = 0; i < 8; ++i) {
                const int c = i * 256 + tid;
                const int nl = c >> 4;
                const u16x8 v = *(const u16x8*)&smem[c * 8];
                const int mch = (c & 15) ^ (nl & 15);
                const int hd = (n0 - 4096) + nl;
                *(u16x8*)&Vt[((size_t)(bb * 2048 + hd)) * 2048 + (m0 & 2047) + mch * 8] = v;
            }
        }
    } else {
        const int mg0 = m0 + wy * 64 + qd * 4;
        const int ng0 = n0 + wx * 64 + ln;
#pragma unroll
        for (int mi = 0; mi < 4; ++mi)
#pragma unroll
            for (int ni = 0; ni < 4; ++ni) {
                const int ng = ng0 + ni * 16;
#pragma unroll
                for (int r = 0; r < 4; ++r)
                    Out[(size_t)(mg0 + mi * 16 + r) * 2048 + ng] = acc[mi][ni][r];
            }
    }
}

// ---------------- causal flash attention, dbuf K/V, single barrier/iter ----------------
__global__ __launch_bounds__(256, 2) void attn_kernel(const u16* __restrict__ Qb, const u16* __restrict__ Kb,
                                                      const u16* __restrict__ Vt, u16* __restrict__ Yb) {
    extern __shared__ u16 smem[];
    u16* QP = smem;                 // 8192 u16
    u16* KsB = smem + 8192;         // 2 x 8192 u16
    u16* VsB = smem + 8192 + 16384; // 2 x 8192 u16

    const int tid = threadIdx.x;
    const int lane = tid & 63;
    const int qd = lane >> 4, ln = lane & 15;
    const int wid = tid >> 6;
    const int wr = wid * 32;
    const int qt = (int)(gridDim.x - 1 - blockIdx.x);   // LPT: big tiles first
    const int bh = blockIdx.y;
    const int b = bh >> 4, h = bh & 15;
    const int q0 = qt * 128;
    const int wq = q0 + wr;
    const int nkt = 2 * qt + 2;

    const u16* Qbh = Qb + ((size_t)b * 2048 * 16 + h) * 128;
    const u16* Kbh = Kb + ((size_t)b * 2048 * 16 + h) * 128;
    const u16* Vbh = Vt + ((size_t)(b * 16 + h) * 128) * 2048;

    const u16* gK[4]; const u16* gV[4]; int lC[4];
#pragma unroll
    for (int p = 0; p < 4; ++p) {
        const int c = p * 256 + tid;
        lC[p] = c * 8;
        { const int r = c >> 4, cc = (c & 15) ^ (r & 7);
          gK[p] = Kbh + (size_t)r * 2048 + cc * 8; }
        { const int rv = c >> 3, cc = (c & 7) ^ (rv & 7);
          gV[p] = Vbh + (size_t)rv * 2048 + cc * 8; }
    }

#pragma unroll
    for (int p = 0; p < 4; ++p) GLL16(gK[p], &KsB[lC[p]]);
#pragma unroll
    for (int p = 0; p < 4; ++p) GLL16(gV[p], &VsB[lC[p]]);
#pragma unroll
    for (int p = 0; p < 4; ++p) { gK[p] += 64 * 2048; gV[p] += 64; }

    bf16x8 qf[2][4];
#pragma unroll
    for (int p = 0; p < 4; ++p) {
        const int c = p * 256 + tid, lr = c >> 4, cc = (c & 15) ^ (lr & 7);
        GLL16(Qbh + (size_t)(q0 + lr) * 2048 + cc * 8, &QP[c * 8]);
    }
    __syncthreads();
    const int lrb = (wid & 1) * 32;
    if (wid < 2) {
#pragma unroll
        for (int mi = 0; mi < 2; ++mi)
#pragma unroll
            for (int ks = 0; ks < 4; ++ks) {
                const int lr = lrb + mi * 16 + ln;
                qf[mi][ks] = *(const bf16x8*)&QP[lr * 128 + (((ks * 4 + qd) ^ (lr & 7)) * 8)];
            }
    }
    __syncthreads();
#pragma unroll
    for (int p = 0; p < 4; ++p) {
        const int c = p * 256 + tid, lr = c >> 4, cc = (c & 15) ^ (lr & 7);
        GLL16(Qbh + (size_t)(q0 + 64 + lr) * 2048 + cc * 8, &QP[c * 8]);
    }
    __syncthreads();
    if (wid >= 2) {
#pragma unroll
        for (int mi = 0; mi < 2; ++mi)
#pragma unroll
            for (int ks = 0; ks < 4; ++ks) {
                const int lr = lrb + mi * 16 + ln;
                qf[mi][ks] = *(const bf16x8*)&QP[lr * 128 + (((ks * 4 + qd) ^ (lr & 7)) * 8)];
            }
    }
    __syncthreads();

    bf16x8 onesf;
#pragma unroll
    for (int i = 0; i < 8; ++i) onesf[i] = (__bf16)1.0f;

    f32x4 o[2][8];
#pragma unroll
    for (int mi = 0; mi < 2; ++mi)
#pragma unroll
        for (int di = 0; di < 8; ++di) o[mi][di] = f32x4{0.f, 0.f, 0.f, 0.f};
    f32x4 lacc[2] = { f32x4{0.f,0.f,0.f,0.f}, f32x4{0.f,0.f,0.f,0.f} };
    float Mr[2][4];
#pragma unroll
    for (int mi = 0; mi < 2; ++mi)
#pragma unroll
        for (int r = 0; r < 4; ++r) Mr[mi][r] = -1e30f;

    int curbuf = 0;
    for (int kt = 0; kt < nkt; ++kt) {
        const int k0 = kt * 64;
        __syncthreads();
        if (kt + 1 < nkt) {
            u16* kd = KsB + (curbuf ^ 1) * 8192;
            u16* vd = VsB + (curbuf ^ 1) * 8192;
#pragma unroll
            for (int p = 0; p < 4; ++p) GLL16(gK[p], &kd[lC[p]]);
#pragma unroll
            for (int p = 0; p < 4; ++p) GLL16(gV[p], &vd[lC[p]]);
        }
#pragma unroll
        for (int p = 0; p < 4; ++p) { gK[p] += 64 * 2048; gV[p] += 64; }

        if (k0 <= wq + 31) {
            const u16* Kc = KsB + curbuf * 8192;
            const u16* Vc = VsB + curbuf * 8192;
            f32x4 s[2][4];
#pragma unroll
            for (int mi = 0; mi < 2; ++mi)
#pragma unroll
                for (int ni = 0; ni < 4; ++ni) s[mi][ni] = f32x4{0.f, 0.f, 0.f, 0.f};
#pragma unroll
            for (int ks = 0; ks < 4; ++ks) {
                bf16x8 kf[4];
#pragma unroll
                for (int ni = 0; ni < 4; ++ni) {
                    const int row = ni * 16 + ln;
                    kf[ni] = *(const bf16x8*)&Kc[row * 128 + (((ks * 4 + qd) ^ (ln & 7)) * 8)];
                }
#pragma unroll
                for (int mi = 0; mi < 2; ++mi)
#pragma unroll
                    for (int ni = 0; ni < 4; ++ni)
                        s[mi][ni] = mfma16(qf[mi][ks], kf[ni], s[mi][ni]);
            }
            if (k0 + 63 > wq) {
#pragma unroll
                for (int mi = 0; mi < 2; ++mi)
#pragma unroll
                    for (int ni = 0; ni < 4; ++ni)
#pragma unroll
                        for (int r = 0; r < 4; ++r) {
                            const int qi = wq + mi * 16 + qd * 4 + r;
                            const int ki = k0 + ni * 16 + ln;
                            if (ki > qi) s[mi][ni][r] = -1e30f;
                        }
            }
            float rx[2][4];
#pragma unroll
            for (int mi = 0; mi < 2; ++mi)
#pragma unroll
                for (int r = 0; r < 4; ++r)
                    rx[mi][r] = fmaxf(fmaxf(s[mi][0][r], s[mi][1][r]), fmaxf(s[mi][2][r], s[mi][3][r]));
#pragma unroll
            for (int st = 1; st < 16; st <<= 1)
#pragma unroll
                for (int mi = 0; mi < 2; ++mi)
#pragma unroll
                    for (int r = 0; r < 4; ++r)
                        rx[mi][r] = fmaxf(rx[mi][r], __shfl_xor(rx[mi][r], st));
            float al[2][4];
            bool need = false;
#pragma unroll
            for (int mi = 0; mi < 2; ++mi)
#pragma unroll
                for (int r = 0; r < 4; ++r) {
                    const float nm = fmaxf(Mr[mi][r], rx[mi][r]);
                    al[mi][r] = exp2f(Mr[mi][r] - nm);
                    Mr[mi][r] = nm;
                    need |= (al[mi][r] != 1.0f);
                }
            if (__any(need)) {
#pragma unroll
                for (int mi = 0; mi < 2; ++mi) {
#pragma unroll
                    for (int r = 0; r < 4; ++r) lacc[mi][r] *= al[mi][r];
#pragma unroll
                    for (int di = 0; di < 8; ++di)
#pragma unroll
                        for (int r = 0; r < 4; ++r) o[mi][di][r] *= al[mi][r];
                }
            }
#pragma unroll
            for (int mi = 0; mi < 2; ++mi)
#pragma unroll
                for (int ni = 0; ni < 4; ++ni) {
                    const int cc0 = ni * 2 + (ln >> 3);
#pragma unroll
                    for (int r = 0; r < 4; ++r) {
                        const float p = exp2f(s[mi][ni][r] - Mr[mi][r]);
                        const int prow = wr + mi * 16 + qd * 4 + r;
                        QP[prow * 64 + ((cc0 ^ ((prow >> 1) & 7)) * 8) + (ln & 7)] = f2bf(p);
                    }
                }
#pragma unroll
            for (int ks2 = 0; ks2 < 2; ++ks2) {
                bf16x8 pf[2];
#pragma unroll
                for (int mi = 0; mi < 2; ++mi) {
                    const int prow = wr + mi * 16 + ln;
                    pf[mi] = *(const bf16x8*)&QP[prow * 64 + (((ks2 * 4 + qd) ^ ((prow >> 1) & 7)) * 8)];
                }
                lacc[0] = mfma16(pf[0], onesf, lacc[0]);
                lacc[1] = mfma16(pf[1], onesf, lacc[1]);
#pragma unroll
                for (int di = 0; di < 8; ++di) {
                    const int row = di * 16 + ln;
                    bf16x8 vf = *(const bf16x8*)&Vc[row * 64 + (((ks2 * 4 + qd) ^ (ln & 7)) * 8)];
                    o[0][di] = mfma16(pf[0], vf, o[0][di]);
                    o[1][di] = mfma16(pf[1], vf, o[1][di]);
                }
            }
        }
        curbuf ^= 1;
    }
#pragma unroll
    for (int mi = 0; mi < 2; ++mi) {
        float inv[4];
#pragma unroll
        for (int r = 0; r < 4; ++r) inv[r] = 1.f / lacc[mi][r];
#pragma unroll
        for (int di = 0; di < 8; ++di)
#pragma unroll
            for (int r = 0; r < 4; ++r) {
                const int t = q0 + wr + mi * 16 + qd * 4 + r;
                const int d = di * 16 + ln;
                Yb[((size_t)((b * 2048 + t) * 16 + h)) * 128 + d] = f2bf(o[mi][di][r] * inv[r]);
            }
    }
}

// ---------------- launch ----------------
extern "C" void kernel_launch(void* const* d_in, const int* in_sizes, int n_in,
                              void* d_out, int out_size, void* d_ws, size_t ws_size,
                              hipStream_t stream) {
    const float* x  = (const float*)d_in[0];
    const float* wq = (const float*)d_in[1];
    const float* wk = (const float*)d_in[2];
    const float* wv = (const float*)d_in[3];
    const float* wo = (const float*)d_in[4];
    float* out = (float*)d_out;
    char* ws = (char*)d_ws;

    u16* xb     = (u16*)(ws);                          // 8192x2048 bf16; reused as Y after attn
    u16* wqkv   = (u16*)(ws + (size_t)33554432);       // 6144x2048 bf16
    u16* wob    = (u16*)(ws + (size_t)58720256);       // 2048x2048 bf16
    u16* Qb     = (u16*)(ws + (size_t)67108864);       // (B,T,H,D) bf16, pre-scaled by 1/sqrt(D)*log2e
    u16* Kb     = (u16*)(ws + (size_t)100663296);      // (B,T,H,D) bf16
    u16* Vt     = (u16*)(ws + (size_t)134217728);      // (B,H,D,T) bf16
    float2* tab = (float2*)(ws + (size_t)167772160);   // 2048x64 cos/sin(2theta)
    u16* Yb = xb;

    const float scl = 0.08838834764831845f * 1.4426950408889634f;

    cvt_f32_bf16<<<16384, 256, 0, stream>>>(x, xb, 4194304);
    cvt_f32_bf16<<<4096, 256, 0, stream>>>(wq, wqkv, 1048576);
    cvt_f32_bf16<<<4096, 256, 0, stream>>>(wk, wqkv + 4194304, 1048576);
    cvt_f32_bf16<<<4096, 256, 0, stream>>>(wv, wqkv + 8388608, 1048576);
    cvt_f32_bf16<<<4096, 256, 0, stream>>>(wo, wob, 1048576);
    rope_table_k<<<512, 256, 0, stream>>>(tab);

    gemm_nt<0><<<dim3(64, 48), 256, 0, stream>>>(xb, wqkv, Qb, Kb, Vt, nullptr, tab, scl, 2048);

    hipFuncSetAttribute((const void*)attn_kernel, hipFuncAttributeMaxDynamicSharedMemorySize, 81920);
    attn_kernel<<<dim3(16, 64), 256, 81920, stream>>>(Qb, Kb, Vt, Yb);

    gemm_nt<1><<<dim3(64, 16), 256, 0, stream>>>(Yb, wob, nullptr, nullptr, nullptr, out, tab, 1.0f, 2048);
}

// Round 2
// 641.282 us; speedup vs baseline: 1.2413x; 1.1244x over previous
//
#include <hip/hip_runtime.h>
#include <math.h>

typedef unsigned short u16;
typedef __attribute__((ext_vector_type(4))) float f32x4;
typedef __attribute__((ext_vector_type(8))) __bf16 bf16x8;
typedef __attribute__((ext_vector_type(4))) unsigned short u16x4;
typedef __attribute__((ext_vector_type(8))) unsigned short u16x8;

// async global->LDS, 16B per lane; LDS dest must be wave-uniform base + lane*16
#define GLL16(gp, lp) __builtin_amdgcn_global_load_lds( \
    (__attribute__((address_space(1))) void*)(void*)(gp), \
    (__attribute__((address_space(3))) void*)(void*)(lp), 16, 0, 0)

__device__ __forceinline__ u16 f2bf(float x) {            // RNE
    unsigned u = __float_as_uint(x);
    return (u16)((u + 0x7FFFu + ((u >> 16) & 1u)) >> 16);
}
__device__ __forceinline__ float bf2f(u16 h) { return __uint_as_float(((unsigned)h) << 16); }

__device__ __forceinline__ f32x4 mfma16(bf16x8 a, bf16x8 b, f32x4 c) {
    return __builtin_amdgcn_mfma_f32_16x16x32_bf16(a, b, c, 0, 0, 0);
}

// ---------------- fp32 -> bf16 conversion ----------------
__global__ void cvt_f32_bf16(const float* __restrict__ s, u16* __restrict__ d, int n4) {
    int i = blockIdx.x * 256 + threadIdx.x;
    if (i < n4) {
        float4 v = ((const float4*)s)[i];
        u16x4 o = { f2bf(v.x), f2bf(v.y), f2bf(v.z), f2bf(v.w) };
        ((u16x4*)d)[i] = o;
    }
}

// ---------------- rope table: cos/sin of 2*theta (double rotary = rotate by 2theta) ----
__global__ void rope_table_k(float2* __restrict__ tab) {
    int id = blockIdx.x * 256 + threadIdx.x;   // 2048*64
    int t = id >> 6, j = id & 63;
    float freq = exp2f(-((float)(2 * j) / 128.f) * 13.287712379549449f);
    float ang = 2.f * (float)t * freq;
    float sv, cv;
    sincosf(ang, &sv, &cv);
    float2 r; r.x = cv; r.y = sv;
    tab[id] = r;
}

// ---------------- NT GEMM: C[m][n] = sum_k A[m][k] * B[n][k], 128x128 tile, BK=64 ----
// Double-buffered LDS, raw s_barrier + counted vmcnt(8); source-side XOR swizzle
// (linear LDS dest for global_load_lds), ds_read applies the same XOR.
// MODE 0: fused QKV; rope+scale fused into Q/K epilogue; V written transposed.
// MODE 1: fp32 Out (M x 2048)
template <int MODE>
__global__ __launch_bounds__(256) void gemm_nt(const u16* __restrict__ A, const u16* __restrict__ Bw,
                                               u16* __restrict__ Qo, u16* __restrict__ Ko,
                                               u16* __restrict__ Vt, float* __restrict__ Out,
                                               const float2* __restrict__ tab, float qscale, int K) {
    __shared__ u16 smem[32768];   // buf b: As at b*16384, Bs at b*16384+8192 (u16 idx)
    const int tid = threadIdx.x;
    const int lane = tid & 63;
    const int qd = lane >> 4, ln = lane & 15;
    const int wid = tid >> 6;
    const int wx = wid & 1, wy = wid >> 1;

    constexpr int NBY = (MODE == 0) ? 48 : 16;
    const int id = blockIdx.y * 64 + blockIdx.x;
    const int xcd = id & 7, slot = id >> 3;
    const int m0 = ((slot / NBY) * 8 + xcd) * 128;
    const int n0 = (slot % NBY) * 128;

    // staging map: tile = 128 rows x 64 k (= 1024 16B chunks), 4 chunks/thread/matrix.
    // LDS dest linear; source k-chunk pre-swizzled: kc_src = kc ^ (row&7).
    int asrc[4], bsrc[4], ldst[4];
#pragma unroll
    for (int l = 0; l < 4; ++l) {
        const int i = l * 256 + tid;
        const int r = i >> 3;
        const int kc = (i & 7) ^ (r & 7);
        asrc[l] = (m0 + r) * K + kc * 8;
        bsrc[l] = (n0 + r) * K + kc * 8;
        ldst[l] = i * 8;
    }
    const u16* Ag = A;
    const u16* Bg = Bw;

    f32x4 acc[4][4];
#pragma unroll
    for (int mi = 0; mi < 4; ++mi)
#pragma unroll
        for (int ni = 0; ni < 4; ++ni) acc[mi][ni] = f32x4{0.f, 0.f, 0.f, 0.f};

    const int arow = (wy * 64 + ln) * 64;      // u16 idx of this lane's A row base
    const int brow = (wx * 64 + ln) * 64;
    const int cx[2] = { (qd ^ (ln & 7)) * 8, ((qd + 4) ^ (ln & 7)) * 8 };  // swizzled k-chunk offs

    auto compute = [&](int buf) {
        const u16* As = &smem[buf * 16384];
        const u16* Bs = As + 8192;
#pragma unroll
        for (int ks = 0; ks < 2; ++ks) {
            bf16x8 af[4], bfr[4];
#pragma unroll
            for (int i = 0; i < 4; ++i) af[i] = *(const bf16x8*)&As[arow + i * 1024 + cx[ks]];
#pragma unroll
            for (int i = 0; i < 4; ++i) bfr[i] = *(const bf16x8*)&Bs[brow + i * 1024 + cx[ks]];
#pragma unroll
            for (int mi = 0; mi < 4; ++mi)
#pragma unroll
                for (int ni = 0; ni < 4; ++ni)
                    acc[mi][ni] = mfma16(af[mi], bfr[ni], acc[mi][ni]);
        }
    };

    const int niter = K >> 6;                  // 32
    // prologue: tile 0 -> buf0
#pragma unroll
    for (int l = 0; l < 4; ++l) GLL16(Ag + asrc[l], &smem[ldst[l]]);
#pragma unroll
    for (int l = 0; l < 4; ++l) GLL16(Bg + bsrc[l], &smem[8192 + ldst[l]]);
    Ag += 64; Bg += 64;

    for (int kt = 0; kt < niter - 1; ++kt) {
        // barrier(1): all waves' prior-iter ds_reads retired -> safe to overwrite buf^1.
        asm volatile("s_barrier" ::: "memory");
        u16* dA = &smem[((kt + 1) & 1) * 16384];
#pragma unroll
        for (int l = 0; l < 4; ++l) GLL16(Ag + asrc[l], &dA[ldst[l]]);
#pragma unroll
        for (int l = 0; l < 4; ++l) GLL16(Bg + bsrc[l], &dA[8192 + ldst[l]]);
        Ag += 64; Bg += 64;
        // counted wait: 8 newer (tile kt+1) loads stay in flight; tile kt landed.
        asm volatile("s_waitcnt vmcnt(8)" ::: "memory");
        asm volatile("s_barrier" ::: "memory");
        compute(kt & 1);
    }
    asm volatile("s_barrier" ::: "memory");
    asm volatile("s_waitcnt vmcnt(0)" ::: "memory");
    asm volatile("s_barrier" ::: "memory");
    compute((niter - 1) & 1);

    __syncthreads();   // K-loop LDS dead; epilogue reuses it

    if constexpr (MODE == 0) {
        const int sec = n0 >> 11;   // 0=Q 1=K 2=V, uniform per block
        if (sec <= 1) {
            // stage C tile [m 128][d 128], chunk-swizzled: chunk' = (d>>3) ^ (m&15)
#pragma unroll
            for (int mi = 0; mi < 4; ++mi)
#pragma unroll
                for (int ni = 0; ni < 4; ++ni) {
                    const int col = wx * 64 + ni * 16 + ln;
                    const int cc = col >> 3, co = col & 7;
#pragma unroll
                    for (int r = 0; r < 4; ++r) {
                        const int row = wy * 64 + mi * 16 + qd * 4 + r;
                        smem[row * 128 + ((cc ^ (row & 15)) * 8) + co] = f2bf(acc[mi][ni][r]);
                    }
                }
            __syncthreads();
            const float qs = (sec == 0) ? qscale : 1.0f;
            u16* dstb = (sec == 0 ? Qo : Ko);
#pragma unroll
            for (int it = 0; it < 4; ++it) {
                const int c = it * 256 + tid;          // 1024 items: m=c>>3 (0..127), d-octet=c&7
                const int m = c >> 3, d8 = c & 7;
                const u16x8 lo = *(const u16x8*)&smem[m * 128 + ((d8 ^ (m & 15)) * 8)];
                const u16x8 hi = *(const u16x8*)&smem[m * 128 + (((d8 + 8) ^ (m & 15)) * 8)];
                const int t = (m0 + m) & 2047;
                const float2* tb = tab + t * 64 + d8 * 8;
                u16x8 o1, o2;
#pragma unroll
                for (int i = 0; i < 8; ++i) {
                    const float x1 = bf2f(lo[i]), x2 = bf2f(hi[i]);
                    const float2 cs = tb[i];
                    o1[i] = f2bf((x1 * cs.x + x2 * cs.y) * qs);
                    o2[i] = f2bf((x2 * cs.x - x1 * cs.y) * qs);
                }
                u16* dst = dstb + (size_t)(m0 + m) * 2048 + (n0 & 2047) + d8 * 8;
                *(u16x8*)dst = o1;
                *(u16x8*)(dst + 64) = o2;
            }
        } else {
            // V transpose: stage [n 128][m 128] chunk-swizzled, stream out rows of Vt
            const int bb = m0 >> 11;
#pragma unroll
            for (int mi = 0; mi < 4; ++mi) {
                const int mbase = wy * 64 + mi * 16 + qd * 4;
                const int mch = mbase >> 3, moff = mbase & 7;
#pragma unroll
                for (int ni = 0; ni < 4; ++ni) {
                    const int nl = wx * 64 + ni * 16 + ln;
                    u16x4 pk = { f2bf(acc[mi][ni][0]), f2bf(acc[mi][ni][1]),
                                 f2bf(acc[mi][ni][2]), f2bf(acc[mi][ni][3]) };
                    *(u16x4*)&smem[nl * 128 + ((mch ^ (nl & 15)) * 8) + moff] = pk;
                }
            }
            __syncthreads();
#pragma unroll
            for (int i = 0; i < 8; ++i) {
                const int c = i * 256 + tid;
                const int nl = c >> 4;
                const u16x8 v = *(const u16x8*)&smem[c * 8];
                const int mch = (c & 15) ^ (nl & 15);
                const int hd = (n0 - 4096) + nl;
                *(u16x8*)&Vt[((size_t)(bb * 2048 + hd)) * 2048 + (m0 & 2047) + mch * 8] = v;
            }
        }
    } else {
        const int mg0 = m0 + wy * 64 + qd * 4;
        const int ng0 = n0 + wx * 64 + ln;
#pragma unroll
        for (int mi = 0; mi < 4; ++mi)
#pragma unroll
            for (int ni = 0; ni < 4; ++ni) {
                const int ng = ng0 + ni * 16;
#pragma unroll
                for (int r = 0; r < 4; ++r)
                    Out[(size_t)(mg0 + mi * 16 + r) * 2048 + ng] = acc[mi][ni][r];
            }
    }
}

// ---------------- causal flash attention ----------------
// 512 threads (8 waves x 16 q-rows), paired q-tiles {15-px, px} per block -> every
// block does exactly 34 k-iterations (perfect balance). 80KB LDS -> 2 blocks/CU ->
// 16 waves/CU. K-loop: raw s_barrier + counted vmcnt(4) (loads span the barrier).
// ID map: px = id>>6, bh = id&63 -> the 8 px-siblings sharing one (b,h) K/V stream
// land on the same XCD (id mod 8 == bh mod 8) for L2 reuse.
__global__ __launch_bounds__(512, 4) void attn_kernel(const u16* __restrict__ Qb, const u16* __restrict__ Kb,
                                                      const u16* __restrict__ Vt, u16* __restrict__ Yb) {
    extern __shared__ u16 smem[];
    u16* QP = smem;                 // 8192 u16: Q stage (64x128) / P buf (128x64)
    u16* KsB = smem + 8192;         // 2 x 8192 u16
    u16* VsB = smem + 8192 + 16384; // 2 x 8192 u16

    const int tid = threadIdx.x;
    const int lane = tid & 63;
    const int qd = lane >> 4, ln = lane & 15;
    const int wid = tid >> 6;            // 0..7
    const int id = (int)blockIdx.x;
    const int px = id >> 6;              // 0..7
    const int bh = id & 63;
    const int b = bh >> 4, h = bh & 15;

    const u16* Qbh = Qb + ((size_t)b * 2048 * 16 + h) * 128;
    const u16* Kbh = Kb + ((size_t)b * 2048 * 16 + h) * 128;
    const u16* Vbh = Vt + ((size_t)(b * 16 + h) * 128) * 2048;

    // staging maps: 1024 16B chunks per tile, 2 chunks/thread.
    // K/Q tile: 64 rows x 128 d, row-chunk swizzle cc = (c&15)^(r&7).
    // V tile: 128 rows x 64 t, cc = (c&7)^(rv&7).
    int lC[2], kOff[2], vOff[2];
#pragma unroll
    for (int p = 0; p < 2; ++p) {
        const int c = p * 512 + tid;     // 0..1023
        lC[p] = c * 8;
        { const int r = c >> 4, cc = (c & 15) ^ (r & 7); kOff[p] = r * 2048 + cc * 8; }
        { const int rv = c >> 3, cc = (c & 7) ^ (rv & 7); vOff[p] = rv * 2048 + cc * 8; }
    }

    bf16x8 onesf;
#pragma unroll
    for (int i = 0; i < 8; ++i) onesf[i] = (__bf16)1.0f;

    for (int half = 0; half < 2; ++half) {
        const int qt = half ? px : (15 - px);   // heavy tile first
        const int q0 = qt * 128;
        const int wq = q0 + wid * 16;
        const int nkt = 2 * qt + 2;

        __syncthreads();   // all waves done with QP (P buffer) before restaging Q
        // ---- stage Q rows q0..q0+63, waves 0..3 grab fragments ----
#pragma unroll
        for (int p = 0; p < 2; ++p)
            GLL16(Qbh + (size_t)q0 * 2048 + kOff[p], &QP[lC[p]]);
        __syncthreads();
        bf16x8 qf[4];
        if (wid < 4) {
            const int lr = wid * 16 + ln;
#pragma unroll
            for (int ks = 0; ks < 4; ++ks)
                qf[ks] = *(const bf16x8*)&QP[lr * 128 + (((ks * 4 + qd) ^ (lr & 7)) * 8)];
        }
        __syncthreads();
        // ---- stage Q rows q0+64..q0+127, waves 4..7 grab fragments ----
#pragma unroll
        for (int p = 0; p < 2; ++p)
            GLL16(Qbh + (size_t)(q0 + 64) * 2048 + kOff[p], &QP[lC[p]]);
        __syncthreads();
        if (wid >= 4) {
            const int lr = (wid - 4) * 16 + ln;
#pragma unroll
            for (int ks = 0; ks < 4; ++ks)
                qf[ks] = *(const bf16x8*)&QP[lr * 128 + (((ks * 4 + qd) ^ (lr & 7)) * 8)];
        }
        __syncthreads();   // readers drained before k-loop P writes reuse QP

        // ---- K/V prologue: tile 0 -> buf 0 ----
#pragma unroll
        for (int p = 0; p < 2; ++p) GLL16(Kbh + kOff[p], &KsB[lC[p]]);
#pragma unroll
        for (int p = 0; p < 2; ++p) GLL16(Vbh + vOff[p], &VsB[lC[p]]);

        f32x4 o[8];
#pragma unroll
        for (int di = 0; di < 8; ++di) o[di] = f32x4{0.f, 0.f, 0.f, 0.f};
        f32x4 lacc = f32x4{0.f, 0.f, 0.f, 0.f};
        float Mr[4];
#pragma unroll
        for (int r = 0; r < 4; ++r) Mr[r] = -1e30f;

        for (int kt = 0; kt < nkt; ++kt) {
            const int k0 = kt * 64;
            // barrier(1): all waves' reads of buf (kt+1)&1 (from iter kt-1) retired.
            asm volatile("s_barrier" ::: "memory");
            if (kt + 1 < nkt) {
                u16* kd = KsB + ((kt + 1) & 1) * 8192;
                u16* vd = VsB + ((kt + 1) & 1) * 8192;
#pragma unroll
                for (int p = 0; p < 2; ++p) GLL16(Kbh + (size_t)(k0 + 64) * 2048 + kOff[p], &kd[lC[p]]);
#pragma unroll
                for (int p = 0; p < 2; ++p) GLL16(Vbh + (size_t)(k0 + 64) + vOff[p], &vd[lC[p]]);
                // 4 newer (tile kt+1) loads stay in flight; tile kt landed.
                asm volatile("s_waitcnt vmcnt(4)" ::: "memory");
            } else {
                asm volatile("s_waitcnt vmcnt(0)" ::: "memory");
            }
            asm volatile("s_barrier" ::: "memory");

            if (k0 <= wq + 15) {
                const u16* Kc = KsB + (kt & 1) * 8192;
                const u16* Vc = VsB + (kt & 1) * 8192;
                f32x4 s[4];
#pragma unroll
                for (int ni = 0; ni < 4; ++ni) s[ni] = f32x4{0.f, 0.f, 0.f, 0.f};
#pragma unroll
                for (int ks = 0; ks < 4; ++ks) {
                    bf16x8 kf[4];
#pragma unroll
                    for (int ni = 0; ni < 4; ++ni) {
                        const int row = ni * 16 + ln;
                        kf[ni] = *(const bf16x8*)&Kc[row * 128 + (((ks * 4 + qd) ^ (ln & 7)) * 8)];
                    }
#pragma unroll
                    for (int ni = 0; ni < 4; ++ni)
                        s[ni] = mfma16(qf[ks], kf[ni], s[ni]);
                }
                if (k0 + 63 > wq) {
#pragma unroll
                    for (int ni = 0; ni < 4; ++ni)
#pragma unroll
                        for (int r = 0; r < 4; ++r) {
                            const int qi = wq + qd * 4 + r;
                            const int ki = k0 + ni * 16 + ln;
                            if (ki > qi) s[ni][r] = -1e30f;
                        }
                }
                float rx[4];
#pragma unroll
                for (int r = 0; r < 4; ++r)
                    rx[r] = fmaxf(fmaxf(s[0][r], s[1][r]), fmaxf(s[2][r], s[3][r]));
#pragma unroll
                for (int st = 1; st < 16; st <<= 1)
#pragma unroll
                    for (int r = 0; r < 4; ++r)
                        rx[r] = fmaxf(rx[r], __shfl_xor(rx[r], st));
                float al[4];
                bool need = false;
#pragma unroll
                for (int r = 0; r < 4; ++r) {
                    const float nm = fmaxf(Mr[r], rx[r]);
                    al[r] = exp2f(Mr[r] - nm);
                    Mr[r] = nm;
                    need |= (al[r] != 1.0f);
                }
                if (__any(need)) {
#pragma unroll
                    for (int r = 0; r < 4; ++r) lacc[r] *= al[r];
#pragma unroll
                    for (int di = 0; di < 8; ++di)
#pragma unroll
                        for (int r = 0; r < 4; ++r) o[di][r] *= al[r];
                }
#pragma unroll
                for (int ni = 0; ni < 4; ++ni) {
                    const int cc0 = ni * 2 + (ln >> 3);
#pragma unroll
                    for (int r = 0; r < 4; ++r) {
                        const float p = exp2f(s[ni][r] - Mr[r]);
                        const int prow = wid * 16 + qd * 4 + r;
                        QP[prow * 64 + ((cc0 ^ ((prow >> 1) & 7)) * 8) + (ln & 7)] = f2bf(p);
                    }
                }
#pragma unroll
                for (int ks2 = 0; ks2 < 2; ++ks2) {
                    const int prow = wid * 16 + ln;
                    bf16x8 pf = *(const bf16x8*)&QP[prow * 64 + (((ks2 * 4 + qd) ^ ((prow >> 1) & 7)) * 8)];
                    lacc = mfma16(pf, onesf, lacc);
#pragma unroll
                    for (int di = 0; di < 8; ++di) {
                        const int row = di * 16 + ln;
                        bf16x8 vf = *(const bf16x8*)&Vc[row * 64 + (((ks2 * 4 + qd) ^ (ln & 7)) * 8)];
                        o[di] = mfma16(pf, vf, o[di]);
                    }
                }
            }
        }

        // ---- epilogue for this q-tile ----
        float inv[4];
#pragma unroll
        for (int r = 0; r < 4; ++r) inv[r] = 1.f / lacc[r];
#pragma unroll
        for (int di = 0; di < 8; ++di)
#pragma unroll
            for (int r = 0; r < 4; ++r) {
                const int t = q0 + wid * 16 + qd * 4 + r;
                const int d = di * 16 + ln;
                Yb[((size_t)((b * 2048 + t) * 16 + h)) * 128 + d] = f2bf(o[di][r] * inv[r]);
            }
    }
}

// ---------------- launch ----------------
extern "C" void kernel_launch(void* const* d_in, const int* in_sizes, int n_in,
                              void* d_out, int out_size, void* d_ws, size_t ws_size,
                              hipStream_t stream) {
    const float* x  = (const float*)d_in[0];
    const float* wq = (const float*)d_in[1];
    const float* wk = (const float*)d_in[2];
    const float* wv = (const float*)d_in[3];
    const float* wo = (const float*)d_in[4];
    float* out = (float*)d_out;
    char* ws = (char*)d_ws;

    u16* xb     = (u16*)(ws);                          // 8192x2048 bf16; reused as Y after attn
    u16* wqkv   = (u16*)(ws + (size_t)33554432);       // 6144x2048 bf16
    u16* wob    = (u16*)(ws + (size_t)58720256);       // 2048x2048 bf16
    u16* Qb     = (u16*)(ws + (size_t)67108864);       // (B,T,H,D) bf16, pre-scaled by 1/sqrt(D)*log2e
    u16* Kb     = (u16*)(ws + (size_t)100663296);      // (B,T,H,D) bf16
    u16* Vt     = (u16*)(ws + (size_t)134217728);      // (B,H,D,T) bf16
    float2* tab = (float2*)(ws + (size_t)167772160);   // 2048x64 cos/sin(2theta)
    u16* Yb = xb;

    const float scl = 0.08838834764831845f * 1.4426950408889634f;

    cvt_f32_bf16<<<16384, 256, 0, stream>>>(x, xb, 4194304);
    cvt_f32_bf16<<<4096, 256, 0, stream>>>(wq, wqkv, 1048576);
    cvt_f32_bf16<<<4096, 256, 0, stream>>>(wk, wqkv + 4194304, 1048576);
    cvt_f32_bf16<<<4096, 256, 0, stream>>>(wv, wqkv + 8388608, 1048576);
    cvt_f32_bf16<<<4096, 256, 0, stream>>>(wo, wob, 1048576);
    rope_table_k<<<512, 256, 0, stream>>>(tab);

    gemm_nt<0><<<dim3(64, 48), 256, 0, stream>>>(xb, wqkv, Qb, Kb, Vt, nullptr, tab, scl, 2048);

    hipFuncSetAttribute((const void*)attn_kernel, hipFuncAttributeMaxDynamicSharedMemorySize, 81920);
    attn_kernel<<<dim3(512), 512, 81920, stream>>>(Qb, Kb, Vt, Yb);

    gemm_nt<1><<<dim3(64, 16), 256, 0, stream>>>(Yb, wob, nullptr, nullptr, nullptr, out, tab, 1.0f, 2048);
}

// Round 3
// 546.003 us; speedup vs baseline: 1.4580x; 1.1745x over previous
//
#include <hip/hip_runtime.h>
#include <math.h>

typedef unsigned short u16;
typedef __attribute__((ext_vector_type(4))) float f32x4;
typedef __attribute__((ext_vector_type(8))) __bf16 bf16x8;
typedef __attribute__((ext_vector_type(4))) unsigned short u16x4;
typedef __attribute__((ext_vector_type(8))) unsigned short u16x8;

// async global->LDS, 16B per lane; LDS dest must be wave-uniform base + lane*16
#define GLL16(gp, lp) __builtin_amdgcn_global_load_lds( \
    (__attribute__((address_space(1))) void*)(void*)(gp), \
    (__attribute__((address_space(3))) void*)(void*)(lp), 16, 0, 0)

__device__ __forceinline__ u16 f2bf(float x) {            // RNE
    unsigned u = __float_as_uint(x);
    return (u16)((u + 0x7FFFu + ((u >> 16) & 1u)) >> 16);
}
__device__ __forceinline__ float bf2f(u16 h) { return __uint_as_float(((unsigned)h) << 16); }

__device__ __forceinline__ f32x4 mfma16(bf16x8 a, bf16x8 b, f32x4 c) {
    return __builtin_amdgcn_mfma_f32_16x16x32_bf16(a, b, c, 0, 0, 0);
}

// ---------------- fp32 -> bf16 conversion ----------------
__global__ void cvt_f32_bf16(const float* __restrict__ s, u16* __restrict__ d, int n4) {
    int i = blockIdx.x * 256 + threadIdx.x;
    if (i < n4) {
        float4 v = ((const float4*)s)[i];
        u16x4 o = { f2bf(v.x), f2bf(v.y), f2bf(v.z), f2bf(v.w) };
        ((u16x4*)d)[i] = o;
    }
}

// ---------------- rope table: cos/sin of 2*theta (double rotary = rotate by 2theta) ----
__global__ void rope_table_k(float2* __restrict__ tab) {
    int id = blockIdx.x * 256 + threadIdx.x;   // 2048*64
    int t = id >> 6, j = id & 63;
    float freq = exp2f(-((float)(2 * j) / 128.f) * 13.287712379549449f);
    float ang = 2.f * (float)t * freq;
    float sv, cv;
    sincosf(ang, &sv, &cv);
    float2 r; r.x = cv; r.y = sv;
    tab[id] = r;
}

// ---------------- NT GEMM: C[m][n] = sum_k A[m][k] * B[n][k] ----------------
// 256x256 tile, BK=64, 512 thr / 8 waves (2M x 4N), wave tile 128x64, acc[8][4].
// LDS 128KB dynamic: slot s=t&1 at s*32768 u16: A 256x64 (+0), B 256x64 (+16384).
// Source-side XOR swizzle kc^=row&7 (linear LDS dest for global_load_lds).
// Per K-tile: 4 quadrant phases x 16 MFMA (setprio-wrapped), 1 half-tile staged
// per phase, ONE counted vmcnt(2) per tile (loads span barriers; never drain).
//   tile X halves staged at: (X-2,ph3)=A-h0, (X-1,ph0)=A-h1, (X-1,ph1)=B-h0,
//   (X-1,ph2)=B-h1.  Slot X&1 is write-safe from (X-2)'s ph3 onward because
//   tile X-2's last ds_read is in its ph2, fenced by ph3's top barrier.
// MODE 0: fused QKV; rope+scale epilogue (2 heads per n-tile); V transposed.
// MODE 1: fp32 Out (M x 2048)
template <int MODE>
__global__ __launch_bounds__(512, 2) void gemm_nt(const u16* __restrict__ A, const u16* __restrict__ Bw,
                                                  u16* __restrict__ Qo, u16* __restrict__ Ko,
                                                  u16* __restrict__ Vt, float* __restrict__ Out,
                                                  const float2* __restrict__ tab, float qscale, int K) {
    extern __shared__ u16 smem[];   // 65536 u16 = 128KB
    const int tid = threadIdx.x;
    const int lane = tid & 63;
    const int qd = lane >> 4, ln = lane & 15;
    const int wid = tid >> 6;             // 0..7
    const int wr = wid >> 2, wc = wid & 3;

    constexpr int NBY = (MODE == 0) ? 24 : 8;
    const int id = (int)blockIdx.x;
    const int xcd = id & 7, slot = id >> 3;
    const int m0 = ((slot / NBY) * 8 + xcd) * 256;
    const int n0 = (slot % NBY) * 256;

    // staging geometry: half-tile = 128 rows x 64 k = 1024 chunks, 2/thread
    int sr[2], skc[2];
#pragma unroll
    for (int l = 0; l < 2; ++l) {
        const int i = l * 512 + tid;
        sr[l] = i >> 3;
        skc[l] = (i & 7) ^ (sr[l] & 7);
    }

    auto stage = [&](int tt, int hx) {    // hx: 0=A-h0 1=A-h1 2=B-h0 3=B-h1
        const u16* gp = (hx < 2) ? A : Bw;
        const int x0 = (hx < 2) ? m0 : n0;
        const int h = hx & 1;
        u16* lb = &smem[(tt & 1) * 32768 + (hx >> 1) * 16384 + h * 8192];
#pragma unroll
        for (int l = 0; l < 2; ++l)
            GLL16(gp + (size_t)(x0 + 128 * h + sr[l]) * K + tt * 64 + skc[l] * 8,
                  &lb[(l * 512 + tid) * 8]);
    };

    f32x4 acc[8][4];
#pragma unroll
    for (int mi = 0; mi < 8; ++mi)
#pragma unroll
        for (int ni = 0; ni < 4; ++ni) acc[mi][ni] = f32x4{0.f, 0.f, 0.f, 0.f};

    const int arow = (wr * 128 + ln) * 64;
    const int brow = (wc * 64 + ln) * 64;
    const int cxk[2] = { (qd ^ (ln & 7)) * 8, ((qd + 4) ^ (ln & 7)) * 8 };

    const int niter = K >> 6;   // 32
    // prologue: tile0 all halves + tile1 A-h0 (10 loads)
    stage(0, 0); stage(0, 1); stage(0, 2); stage(0, 3);
    stage(1, 0);

#pragma unroll 2
    for (int t = 0; t < niter; ++t) {
        const u16* As = &smem[(t & 1) * 32768];
        const u16* Bs = As + 16384;
        const bool pf = (t + 1 < niter);
        // ---- ph0: quadrant m0-3 x n0-1 ----
        if (pf) asm volatile("s_waitcnt vmcnt(2)" ::: "memory");
        else    asm volatile("s_waitcnt vmcnt(0)" ::: "memory");
        asm volatile("s_barrier" ::: "memory");
        bf16x8 a0[4][2], b0[2][2];
#pragma unroll
        for (int mi = 0; mi < 4; ++mi)
#pragma unroll
            for (int ks = 0; ks < 2; ++ks)
                a0[mi][ks] = *(const bf16x8*)&As[arow + mi * 1024 + cxk[ks]];
#pragma unroll
        for (int ni = 0; ni < 2; ++ni)
#pragma unroll
            for (int ks = 0; ks < 2; ++ks)
                b0[ni][ks] = *(const bf16x8*)&Bs[brow + ni * 1024 + cxk[ks]];
        if (pf) stage(t + 1, 1);
        __builtin_amdgcn_s_setprio(1);
#pragma unroll
        for (int mi = 0; mi < 4; ++mi)
#pragma unroll
            for (int ni = 0; ni < 2; ++ni)
#pragma unroll
                for (int ks = 0; ks < 2; ++ks)
                    acc[mi][ni] = mfma16(a0[mi][ks], b0[ni][ks], acc[mi][ni]);
        __builtin_amdgcn_s_setprio(0);
        // ---- ph1: quadrant m0-3 x n2-3 ----
        asm volatile("s_barrier" ::: "memory");
        bf16x8 b1[2][2];
#pragma unroll
        for (int ni = 0; ni < 2; ++ni)
#pragma unroll
            for (int ks = 0; ks < 2; ++ks)
                b1[ni][ks] = *(const bf16x8*)&Bs[brow + (ni + 2) * 1024 + cxk[ks]];
        if (pf) stage(t + 1, 2);
        __builtin_amdgcn_s_setprio(1);
#pragma unroll
        for (int mi = 0; mi < 4; ++mi)
#pragma unroll
            for (int ni = 0; ni < 2; ++ni)
#pragma unroll
                for (int ks = 0; ks < 2; ++ks)
                    acc[mi][ni + 2] = mfma16(a0[mi][ks], b1[ni][ks], acc[mi][ni + 2]);
        __builtin_amdgcn_s_setprio(0);
        // ---- ph2: quadrant m4-7 x n0-1 ----
        asm volatile("s_barrier" ::: "memory");
        bf16x8 a1[4][2];
#pragma unroll
        for (int mi = 0; mi < 4; ++mi)
#pragma unroll
            for (int ks = 0; ks < 2; ++ks)
                a1[mi][ks] = *(const bf16x8*)&As[arow + (mi + 4) * 1024 + cxk[ks]];
        if (pf) stage(t + 1, 3);
        __builtin_amdgcn_s_setprio(1);
#pragma unroll
        for (int mi = 0; mi < 4; ++mi)
#pragma unroll
            for (int ni = 0; ni < 2; ++ni)
#pragma unroll
                for (int ks = 0; ks < 2; ++ks)
                    acc[mi + 4][ni] = mfma16(a1[mi][ks], b0[ni][ks], acc[mi + 4][ni]);
        __builtin_amdgcn_s_setprio(0);
        // ---- ph3: quadrant m4-7 x n2-3 (register-only; frees slot t&1 A-h0) ----
        asm volatile("s_barrier" ::: "memory");
        if (t + 2 < niter) stage(t + 2, 0);
        __builtin_amdgcn_s_setprio(1);
#pragma unroll
        for (int mi = 0; mi < 4; ++mi)
#pragma unroll
            for (int ni = 0; ni < 2; ++ni)
#pragma unroll
                for (int ks = 0; ks < 2; ++ks)
                    acc[mi + 4][ni + 2] = mfma16(a1[mi][ks], b1[ni][ks], acc[mi + 4][ni + 2]);
        __builtin_amdgcn_s_setprio(0);
    }
    __syncthreads();   // K-loop LDS dead; epilogue reuses all 128KB

    if constexpr (MODE == 0) {
        const int sec = n0 >> 11;   // 0=Q 1=K 2=V, uniform per block
        if (sec <= 1) {
            // stage C tile [m 256][d 256] bf16, chunk-swizzled: chunk' = (d>>3) ^ (m&15)
#pragma unroll
            for (int mi = 0; mi < 8; ++mi)
#pragma unroll
                for (int ni = 0; ni < 4; ++ni) {
                    const int col = wc * 64 + ni * 16 + ln;
                    const int cc = col >> 3, co = col & 7;
#pragma unroll
                    for (int r = 0; r < 4; ++r) {
                        const int row = wr * 128 + mi * 16 + qd * 4 + r;
                        smem[row * 256 + ((cc ^ (row & 15)) * 8) + co] = f2bf(acc[mi][ni][r]);
                    }
                }
            __syncthreads();
            const float qs = (sec == 0) ? qscale : 1.0f;
            u16* dstb = (sec == 0 ? Qo : Ko);
#pragma unroll
            for (int it = 0; it < 8; ++it) {
                const int c = it * 512 + tid;    // 4096 items: m (256) x head-in-tile (2) x lo-octet (8)
                const int m = c >> 4, hh = (c >> 3) & 1, d8 = c & 7;
                const u16x8 lo = *(const u16x8*)&smem[m * 256 + (((hh * 16 + d8) ^ (m & 15)) * 8)];
                const u16x8 hi = *(const u16x8*)&smem[m * 256 + (((hh * 16 + 8 + d8) ^ (m & 15)) * 8)];
                const int t = (m0 + m) & 2047;
                const float2* tb = tab + t * 64 + d8 * 8;
                u16x8 o1, o2;
#pragma unroll
                for (int i = 0; i < 8; ++i) {
                    const float x1 = bf2f(lo[i]), x2 = bf2f(hi[i]);
                    const float2 cs = tb[i];
                    o1[i] = f2bf((x1 * cs.x + x2 * cs.y) * qs);
                    o2[i] = f2bf((x2 * cs.x - x1 * cs.y) * qs);
                }
                u16* dst = dstb + (size_t)(m0 + m) * 2048 + (n0 & 2047) + hh * 128 + d8 * 8;
                *(u16x8*)dst = o1;
                *(u16x8*)(dst + 64) = o2;
            }
        } else {
            // V transpose: stage [nl 256][m 256] chunk-swizzled, stream rows of Vt
            const int bb = m0 >> 11;
#pragma unroll
            for (int mi = 0; mi < 8; ++mi) {
                const int mbase = wr * 128 + mi * 16 + qd * 4;
                const int mch = mbase >> 3, moff = mbase & 7;
#pragma unroll
                for (int ni = 0; ni < 4; ++ni) {
                    const int nl = wc * 64 + ni * 16 + ln;
                    u16x4 pk = { f2bf(acc[mi][ni][0]), f2bf(acc[mi][ni][1]),
                                 f2bf(acc[mi][ni][2]), f2bf(acc[mi][ni][3]) };
                    *(u16x4*)&smem[nl * 256 + ((mch ^ (nl & 15)) * 8) + moff] = pk;
                }
            }
            __syncthreads();
#pragma unroll
            for (int i = 0; i < 16; ++i) {
                const int c = i * 512 + tid;     // 8192 chunks
                const int nl = c >> 5, ch = c & 31;
                const u16x8 v = *(const u16x8*)&smem[nl * 256 + ch * 8];
                const int mch = ch ^ (nl & 15);
                const int hd = (n0 - 4096) + nl;
                *(u16x8*)&Vt[((size_t)(bb * 2048 + hd)) * 2048 + (m0 & 2047) + mch * 8] = v;
            }
        }
    } else {
        const int mg0 = m0 + wr * 128 + qd * 4;
        const int ng0 = n0 + wc * 64 + ln;
#pragma unroll
        for (int mi = 0; mi < 8; ++mi)
#pragma unroll
            for (int ni = 0; ni < 4; ++ni) {
                const int ng = ng0 + ni * 16;
#pragma unroll
                for (int r = 0; r < 4; ++r)
                    Out[(size_t)(mg0 + mi * 16 + r) * 2048 + ng] = acc[mi][ni][r];
            }
    }
}

// ---------------- causal flash attention ----------------
// 512 threads (8 waves x 16 q-rows), paired q-tiles {15-px, px} per block -> every
// block does exactly 34 k-iterations. 80KB LDS -> 2 blocks/CU -> 16 waves/CU.
// K-loop: raw s_barrier + counted vmcnt(4).
__global__ __launch_bounds__(512, 4) void attn_kernel(const u16* __restrict__ Qb, const u16* __restrict__ Kb,
                                                      const u16* __restrict__ Vt, u16* __restrict__ Yb) {
    extern __shared__ u16 smem[];
    u16* QP = smem;                 // 8192 u16: Q stage (64x128) / P buf (128x64)
    u16* KsB = smem + 8192;         // 2 x 8192 u16
    u16* VsB = smem + 8192 + 16384; // 2 x 8192 u16

    const int tid = threadIdx.x;
    const int lane = tid & 63;
    const int qd = lane >> 4, ln = lane & 15;
    const int wid = tid >> 6;            // 0..7
    const int id = (int)blockIdx.x;
    const int px = id >> 6;              // 0..7
    const int bh = id & 63;
    const int b = bh >> 4, h = bh & 15;

    const u16* Qbh = Qb + ((size_t)b * 2048 * 16 + h) * 128;
    const u16* Kbh = Kb + ((size_t)b * 2048 * 16 + h) * 128;
    const u16* Vbh = Vt + ((size_t)(b * 16 + h) * 128) * 2048;

    int lC[2], kOff[2], vOff[2];
#pragma unroll
    for (int p = 0; p < 2; ++p) {
        const int c = p * 512 + tid;     // 0..1023
        lC[p] = c * 8;
        { const int r = c >> 4, cc = (c & 15) ^ (r & 7); kOff[p] = r * 2048 + cc * 8; }
        { const int rv = c >> 3, cc = (c & 7) ^ (rv & 7); vOff[p] = rv * 2048 + cc * 8; }
    }

    bf16x8 onesf;
#pragma unroll
    for (int i = 0; i < 8; ++i) onesf[i] = (__bf16)1.0f;

    for (int half = 0; half < 2; ++half) {
        const int qt = half ? px : (15 - px);   // heavy tile first
        const int q0 = qt * 128;
        const int wq = q0 + wid * 16;
        const int nkt = 2 * qt + 2;

        __syncthreads();   // all waves done with QP (P buffer) before restaging Q
#pragma unroll
        for (int p = 0; p < 2; ++p)
            GLL16(Qbh + (size_t)q0 * 2048 + kOff[p], &QP[lC[p]]);
        __syncthreads();
        bf16x8 qf[4];
        if (wid < 4) {
            const int lr = wid * 16 + ln;
#pragma unroll
            for (int ks = 0; ks < 4; ++ks)
                qf[ks] = *(const bf16x8*)&QP[lr * 128 + (((ks * 4 + qd) ^ (lr & 7)) * 8)];
        }
        __syncthreads();
#pragma unroll
        for (int p = 0; p < 2; ++p)
            GLL16(Qbh + (size_t)(q0 + 64) * 2048 + kOff[p], &QP[lC[p]]);
        __syncthreads();
        if (wid >= 4) {
            const int lr = (wid - 4) * 16 + ln;
#pragma unroll
            for (int ks = 0; ks < 4; ++ks)
                qf[ks] = *(const bf16x8*)&QP[lr * 128 + (((ks * 4 + qd) ^ (lr & 7)) * 8)];
        }
        __syncthreads();   // readers drained before k-loop P writes reuse QP

#pragma unroll
        for (int p = 0; p < 2; ++p) GLL16(Kbh + kOff[p], &KsB[lC[p]]);
#pragma unroll
        for (int p = 0; p < 2; ++p) GLL16(Vbh + vOff[p], &VsB[lC[p]]);

        f32x4 o[8];
#pragma unroll
        for (int di = 0; di < 8; ++di) o[di] = f32x4{0.f, 0.f, 0.f, 0.f};
        f32x4 lacc = f32x4{0.f, 0.f, 0.f, 0.f};
        float Mr[4];
#pragma unroll
        for (int r = 0; r < 4; ++r) Mr[r] = -1e30f;

        for (int kt = 0; kt < nkt; ++kt) {
            const int k0 = kt * 64;
            asm volatile("s_barrier" ::: "memory");
            if (kt + 1 < nkt) {
                u16* kd = KsB + ((kt + 1) & 1) * 8192;
                u16* vd = VsB + ((kt + 1) & 1) * 8192;
#pragma unroll
                for (int p = 0; p < 2; ++p) GLL16(Kbh + (size_t)(k0 + 64) * 2048 + kOff[p], &kd[lC[p]]);
#pragma unroll
                for (int p = 0; p < 2; ++p) GLL16(Vbh + (size_t)(k0 + 64) + vOff[p], &vd[lC[p]]);
                asm volatile("s_waitcnt vmcnt(4)" ::: "memory");
            } else {
                asm volatile("s_waitcnt vmcnt(0)" ::: "memory");
            }
            asm volatile("s_barrier" ::: "memory");

            if (k0 <= wq + 15) {
                const u16* Kc = KsB + (kt & 1) * 8192;
                const u16* Vc = VsB + (kt & 1) * 8192;
                f32x4 s[4];
#pragma unroll
                for (int ni = 0; ni < 4; ++ni) s[ni] = f32x4{0.f, 0.f, 0.f, 0.f};
#pragma unroll
                for (int ks = 0; ks < 4; ++ks) {
                    bf16x8 kf[4];
#pragma unroll
                    for (int ni = 0; ni < 4; ++ni) {
                        const int row = ni * 16 + ln;
                        kf[ni] = *(const bf16x8*)&Kc[row * 128 + (((ks * 4 + qd) ^ (ln & 7)) * 8)];
                    }
#pragma unroll
                    for (int ni = 0; ni < 4; ++ni)
                        s[ni] = mfma16(qf[ks], kf[ni], s[ni]);
                }
                if (k0 + 63 > wq) {
#pragma unroll
                    for (int ni = 0; ni < 4; ++ni)
#pragma unroll
                        for (int r = 0; r < 4; ++r) {
                            const int qi = wq + qd * 4 + r;
                            const int ki = k0 + ni * 16 + ln;
                            if (ki > qi) s[ni][r] = -1e30f;
                        }
                }
                float rx[4];
#pragma unroll
                for (int r = 0; r < 4; ++r)
                    rx[r] = fmaxf(fmaxf(s[0][r], s[1][r]), fmaxf(s[2][r], s[3][r]));
#pragma unroll
                for (int st = 1; st < 16; st <<= 1)
#pragma unroll
                    for (int r = 0; r < 4; ++r)
                        rx[r] = fmaxf(rx[r], __shfl_xor(rx[r], st));
                float al[4];
                bool need = false;
#pragma unroll
                for (int r = 0; r < 4; ++r) {
                    const float nm = fmaxf(Mr[r], rx[r]);
                    al[r] = exp2f(Mr[r] - nm);
                    Mr[r] = nm;
                    need |= (al[r] != 1.0f);
                }
                if (__any(need)) {
#pragma unroll
                    for (int r = 0; r < 4; ++r) lacc[r] *= al[r];
#pragma unroll
                    for (int di = 0; di < 8; ++di)
#pragma unroll
                        for (int r = 0; r < 4; ++r) o[di][r] *= al[r];
                }
#pragma unroll
                for (int ni = 0; ni < 4; ++ni) {
                    const int cc0 = ni * 2 + (ln >> 3);
#pragma unroll
                    for (int r = 0; r < 4; ++r) {
                        const float p = exp2f(s[ni][r] - Mr[r]);
                        const int prow = wid * 16 + qd * 4 + r;
                        QP[prow * 64 + ((cc0 ^ ((prow >> 1) & 7)) * 8) + (ln & 7)] = f2bf(p);
                    }
                }
#pragma unroll
                for (int ks2 = 0; ks2 < 2; ++ks2) {
                    const int prow = wid * 16 + ln;
                    bf16x8 pf = *(const bf16x8*)&QP[prow * 64 + (((ks2 * 4 + qd) ^ ((prow >> 1) & 7)) * 8)];
                    lacc = mfma16(pf, onesf, lacc);
#pragma unroll
                    for (int di = 0; di < 8; ++di) {
                        const int row = di * 16 + ln;
                        bf16x8 vf = *(const bf16x8*)&Vc[row * 64 + (((ks2 * 4 + qd) ^ (ln & 7)) * 8)];
                        o[di] = mfma16(pf, vf, o[di]);
                    }
                }
            }
        }

        float inv[4];
#pragma unroll
        for (int r = 0; r < 4; ++r) inv[r] = 1.f / lacc[r];
#pragma unroll
        for (int di = 0; di < 8; ++di)
#pragma unroll
            for (int r = 0; r < 4; ++r) {
                const int t = q0 + wid * 16 + qd * 4 + r;
                const int d = di * 16 + ln;
                Yb[((size_t)((b * 2048 + t) * 16 + h)) * 128 + d] = f2bf(o[di][r] * inv[r]);
            }
    }
}

// ---------------- launch ----------------
extern "C" void kernel_launch(void* const* d_in, const int* in_sizes, int n_in,
                              void* d_out, int out_size, void* d_ws, size_t ws_size,
                              hipStream_t stream) {
    const float* x  = (const float*)d_in[0];
    const float* wq = (const float*)d_in[1];
    const float* wk = (const float*)d_in[2];
    const float* wv = (const float*)d_in[3];
    const float* wo = (const float*)d_in[4];
    float* out = (float*)d_out;
    char* ws = (char*)d_ws;

    u16* xb     = (u16*)(ws);                          // 8192x2048 bf16; reused as Y after attn
    u16* wqkv   = (u16*)(ws + (size_t)33554432);       // 6144x2048 bf16
    u16* wob    = (u16*)(ws + (size_t)58720256);       // 2048x2048 bf16
    u16* Qb     = (u16*)(ws + (size_t)67108864);       // (B,T,H,D) bf16, pre-scaled by 1/sqrt(D)*log2e
    u16* Kb     = (u16*)(ws + (size_t)100663296);      // (B,T,H,D) bf16
    u16* Vt     = (u16*)(ws + (size_t)134217728);      // (B,H,D,T) bf16
    float2* tab = (float2*)(ws + (size_t)167772160);   // 2048x64 cos/sin(2theta)
    u16* Yb = xb;

    const float scl = 0.08838834764831845f * 1.4426950408889634f;

    cvt_f32_bf16<<<16384, 256, 0, stream>>>(x, xb, 4194304);
    cvt_f32_bf16<<<4096, 256, 0, stream>>>(wq, wqkv, 1048576);
    cvt_f32_bf16<<<4096, 256, 0, stream>>>(wk, wqkv + 4194304, 1048576);
    cvt_f32_bf16<<<4096, 256, 0, stream>>>(wv, wqkv + 8388608, 1048576);
    cvt_f32_bf16<<<4096, 256, 0, stream>>>(wo, wob, 1048576);
    rope_table_k<<<512, 256, 0, stream>>>(tab);

    hipFuncSetAttribute((const void*)gemm_nt<0>, hipFuncAttributeMaxDynamicSharedMemorySize, 131072);
    hipFuncSetAttribute((const void*)gemm_nt<1>, hipFuncAttributeMaxDynamicSharedMemorySize, 131072);

    gemm_nt<0><<<dim3(768), 512, 131072, stream>>>(xb, wqkv, Qb, Kb, Vt, nullptr, tab, scl, 2048);

    hipFuncSetAttribute((const void*)attn_kernel, hipFuncAttributeMaxDynamicSharedMemorySize, 81920);
    attn_kernel<<<dim3(512), 512, 81920, stream>>>(Qb, Kb, Vt, Yb);

    gemm_nt<1><<<dim3(256), 512, 131072, stream>>>(Yb, wob, nullptr, nullptr, nullptr, out, tab, 1.0f, 2048);
}